// Round 14
// baseline (274.311 us; speedup 1.0000x reference)
//
#include <hip/hip_runtime.h>
#include <hip/hip_bf16.h>
#include <cstdint>

#define B_   2
#define N_   1024
#define DN_  128
#define DE_  16
#define DG_  128
#define MID_ 64
#define OUT_ 128
#define TI_  2
#define PR_ROWS 4

typedef short bf16x8 __attribute__((ext_vector_type(8)));
typedef float f32x4  __attribute__((ext_vector_type(4)));

__device__ inline short f2bf(float f) {
    union { float f; unsigned u; } v; v.f = f;
    unsigned r = v.u + 0x7FFFu + ((v.u >> 16) & 1u);   // RTNE
    return (short)(unsigned short)(r >> 16);
}

__device__ inline unsigned pk2(float lo, float hi) {
    union { __hip_bfloat162 h; unsigned u; } p;
    p.h = __float22bfloat162_rn(make_float2(lo, hi));  // v_cvt_pk_bf16_f32
    return p.u;
}

// ---------------------------------------------------------------------------
// Fused prep kernel (R10 version — 8-wide load batching, kept).
// ---------------------------------------------------------------------------
__global__ void __launch_bounds__(384) prep_all(
    const float* __restrict__ features, const float* __restrict__ g_features,
    const float* __restrict__ Wm, const float* __restrict__ bm,
    const float* __restrict__ Wskip, const float* __restrict__ bskip,
    const float* __restrict__ W1, const float* __restrict__ b1,
    const float* __restrict__ W2, const float* __restrict__ b2,
    const float* __restrict__ We, const float* __restrict__ be,
    const float* __restrict__ Wg, const float* __restrict__ bg,
    float* __restrict__ values, float* __restrict__ skipo,
    float* __restrict__ P1x, float* __restrict__ p2,
    float* __restrict__ pg, short* __restrict__ We_frag)
{
    const int t   = threadIdx.x;
    const int blk = blockIdx.x;

    if (blk == 512) {                       // --- We fragment prep ---
        for (int e = t; e < 4 * 64 * 8; e += 384) {
            const int c    = e >> 9;
            const int lane = (e >> 3) & 63;
            const int j    = e & 7;
            const int quad = lane >> 4, s = lane & 15;
            short v = 0;
            if (quad < 2) v = f2bf(We[(quad * 8 + j) * MID_ + c * 16 + s]);
            We_frag[e] = v;
        }
        return;
    }
    if (blk == 513) {                       // --- pg ---
        if (t < MID_) {
            float a0 = bg[t], a1 = bg[t];
            for (int k0 = 0; k0 < DG_; k0 += 8) {
                float w[8];
                #pragma unroll
                for (int u = 0; u < 8; ++u) w[u] = Wg[(k0 + u) * MID_ + t];
                #pragma unroll
                for (int u = 0; u < 8; ++u) {
                    a0 += g_features[k0 + u] * w[u];
                    a1 += g_features[DG_ + k0 + u] * w[u];
                }
            }
            pg[t] = a0; pg[MID_ + t] = a1;
        }
        return;
    }

    // --- per-node projections ---
    const int r0 = blk * PR_ROWS;
    __shared__ float feat[PR_ROWS][DN_];
    for (int idx = t; idx < PR_ROWS * DN_; idx += 384)
        feat[idx >> 7][idx & 127] = features[(size_t)r0 * DN_ + idx];
    __syncthreads();

    const float* W; int c, stride; float base; float* outp; int ostride;
    if (t < 128) {
        W = Wm;    c = t;       stride = OUT_; base = bm[c];
        outp = values + (size_t)r0 * OUT_ + c; ostride = OUT_;
    } else if (t < 256) {
        W = Wskip; c = t - 128; stride = OUT_; base = bskip[c];
        outp = skipo + (size_t)r0 * OUT_ + c;  ostride = OUT_;
    } else if (t < 320) {
        W = W1;    c = t - 256; stride = MID_; base = b1[c] + be[c];
        outp = P1x + (size_t)r0 * MID_ + c;    ostride = MID_;
    } else {
        W = W2;    c = t - 320; stride = MID_; base = b2[c];
        outp = p2 + (size_t)r0 * MID_ + c;     ostride = MID_;
    }

    float acc[PR_ROWS] = {};
    for (int k0 = 0; k0 < DN_; k0 += 8) {
        float w[8];
        #pragma unroll
        for (int u = 0; u < 8; ++u) w[u] = W[(k0 + u) * stride + c];
        #pragma unroll
        for (int u = 0; u < 8; ++u)
            #pragma unroll
            for (int q = 0; q < PR_ROWS; ++q) acc[q] += feat[q][k0 + u] * w[u];
    }
    #pragma unroll
    for (int q = 0; q < PR_ROWS; ++q) outp[q * ostride] = acc[q] + base;
}

// ---------------------------------------------------------------------------
// Main fused kernel (R14): R13 structure + per-block PHASE STAGGER.
// R13 post-mortem: instruction diet neutral -> VALU stream already minimal;
// the ~50us beyond VALU-issue is stall. Diagnosis: all 1024 blocks run
// identical code in near-lockstep, so the 4 waves/SIMD (from 4 different
// blocks) hit VMEM-issue and wait windows at the SAME program points --
// correlated stalls defeat TLP (and explain why per-wave ILP depth changes
// were neutral). Fix: stagger each block's iteration phase:
//  - Pass A: tile order rotated by (r*5)&15 (all 16 tiles still covered;
//    buffer rotation stays compile-time under the full unroll).
//  - Pass C: k order rotated by r&63.
// Caches unaffected (values/P1x L2-resident any order; e rows block-private).
// ---------------------------------------------------------------------------
__global__ void __launch_bounds__(256) gat_main(
    const float* __restrict__ e_features, const float* __restrict__ adj,
    const short* __restrict__ We_frag, const float* __restrict__ Wa,
    const float* __restrict__ values, const float* __restrict__ skipo,
    const float* __restrict__ P1x, const float* __restrict__ p2,
    const float* __restrict__ pg, float* __restrict__ out)
{
    const int t    = threadIdx.x;
    const int wv   = t >> 6;                          // 0..3
    const int l    = t & 63;
    const int quad = l >> 4;
    const int s    = l & 15;
    const int r    = blockIdx.x;
    const int b    = (r >> 2) & 1;                    // XCD r%8 -> one batch
    const int i0   = (((r >> 3) << 2) | (r & 3)) * TI_;

    __shared__ float lgP[TI_][N_];
    __shared__ float redv[4][16][20];
    __shared__ float sinv[TI_];
    __shared__ float pmax[4];
    __shared__ float psum[4];

    // ---- block constants ----
    bf16x8 bfr[4];                                    // We A-fragments
    float  wa_s[4][4];                                // Wa, statically indexed
    f32x4  p2l[TI_][4];                               // p2+pg as MFMA C-operand
    #pragma unroll
    for (int c = 0; c < 4; ++c) {
        bfr[c] = *(const bf16x8*)&We_frag[(c * 64 + l) * 8];
        const float4 w4 = *(const float4*)&Wa[c * 16 + quad * 4];
        wa_s[c][0] = w4.x; wa_s[c][1] = w4.y; wa_s[c][2] = w4.z; wa_s[c][3] = w4.w;
        const float4 pg4 = *(const float4*)&pg[b * MID_ + c * 16 + quad * 4];
        #pragma unroll
        for (int ii = 0; ii < TI_; ++ii) {
            const float4 p4 = *(const float4*)&p2[((size_t)(b * N_ + i0 + ii)) * MID_ + c * 16 + quad * 4];
            p2l[ii][c][0] = p4.x + pg4.x;
            p2l[ii][c][1] = p4.y + pg4.y;
            p2l[ii][c][2] = p4.z + pg4.z;
            p2l[ii][c][3] = p4.w + pg4.w;
        }
    }

    // ---- precomputed base pointers ----
    const float* eBase = e_features
        + ((size_t)(b * N_ + i0) * N_ + (size_t)(wv * 16 + s)) * DE_ + quad * 8;
    const float* pBase = P1x + (size_t)(b * N_ + wv * 16 + s) * MID_ + quad * 4;
    // per-it strides (floats): e tile: 1024 ; ii: 16384 ; bias tile: 4096

    const int phA = (r * 5) & 15;                     // per-block phase stagger

    float4 eA[2][TI_][2];                             // 2-deep e rotation
    float  bb[3][4][4];                               // bias, distance-2 rotation

    union AU { unsigned u[4]; bf16x8 v; };
    AU aU[TI_];
    #pragma unroll
    for (int ii = 0; ii < TI_; ++ii) {
        aU[ii].u[0] = 0u; aU[ii].u[1] = 0u; aU[ii].u[2] = 0u; aU[ii].u[3] = 0u;
    }

    // ---- Pass A prologue: tiles phA, phA+1 in flight ----
    {
        const int it0 = phA, it1 = (phA + 1) & 15;
        if (quad < 2) {
            #pragma unroll
            for (int ii = 0; ii < TI_; ++ii) {
                eA[0][ii][0] = *(const float4*)(eBase + ii * 16384 + it0 * 1024);
                eA[0][ii][1] = *(const float4*)(eBase + ii * 16384 + it0 * 1024 + 4);
                eA[1][ii][0] = *(const float4*)(eBase + ii * 16384 + it1 * 1024);
                eA[1][ii][1] = *(const float4*)(eBase + ii * 16384 + it1 * 1024 + 4);
            }
        }
        #pragma unroll
        for (int c = 0; c < 4; ++c) {
            const float4 v0 = *(const float4*)(pBase + it0 * 4096 + c * 16);
            bb[0][c][0] = v0.x; bb[0][c][1] = v0.y; bb[0][c][2] = v0.z; bb[0][c][3] = v0.w;
            const float4 v1 = *(const float4*)(pBase + it1 * 4096 + c * 16);
            bb[1][c][0] = v1.x; bb[1][c][1] = v1.y; bb[1][c][2] = v1.z; bb[1][c][3] = v1.w;
        }
    }

    #pragma unroll
    for (int it = 0; it < 16; ++it) {                 // buffers static; tiles staggered
        const int itp = (it + phA) & 15;              // this iteration's tile phase
        const int j0  = (wv + itp * 4) * 16;

        // pack current e -> persistent fragments (exec-masked, quads 0-1)
        if (quad < 2) {
            #pragma unroll
            for (int ii = 0; ii < TI_; ++ii) {
                aU[ii].u[0] = pk2(eA[it & 1][ii][0].x, eA[it & 1][ii][0].y);
                aU[ii].u[1] = pk2(eA[it & 1][ii][0].z, eA[it & 1][ii][0].w);
                aU[ii].u[2] = pk2(eA[it & 1][ii][1].x, eA[it & 1][ii][1].y);
                aU[ii].u[3] = pk2(eA[it & 1][ii][1].z, eA[it & 1][ii][1].w);
            }
        }
        // refill this e-buffer with tile (it+2)'s phase
        if (it < 14) {
            const int itp2 = (it + 2 + phA) & 15;
            if (quad < 2) {
                #pragma unroll
                for (int ii = 0; ii < TI_; ++ii) {
                    eA[it & 1][ii][0] = *(const float4*)(eBase + ii * 16384 + itp2 * 1024);
                    eA[it & 1][ii][1] = *(const float4*)(eBase + ii * 16384 + itp2 * 1024 + 4);
                }
            }
            #pragma unroll
            for (int c = 0; c < 4; ++c) {
                const float4 v = *(const float4*)(pBase + itp2 * 4096 + c * 16);
                bb[(it + 2) % 3][c][0] = v.x; bb[(it + 2) % 3][c][1] = v.y;
                bb[(it + 2) % 3][c][2] = v.z; bb[(it + 2) % 3][c][3] = v.w;
            }
        }

        __builtin_amdgcn_s_setprio(1);
        #pragma unroll
        for (int ii = 0; ii < TI_; ++ii) {
            f32x4 acc[4];
            #pragma unroll
            for (int c = 0; c < 4; ++c)
                acc[c] = __builtin_amdgcn_mfma_f32_16x16x32_bf16(bfr[c], aU[ii].v, p2l[ii][c], 0, 0, 0);
            // epilogue: leaky-relu + dot(Wa) as a reduction tree
            float tc[4];
            #pragma unroll
            for (int c = 0; c < 4; ++c) {
                float x0 = acc[c][0] + bb[it % 3][c][0];
                float x1 = acc[c][1] + bb[it % 3][c][1];
                float x2 = acc[c][2] + bb[it % 3][c][2];
                float x3 = acc[c][3] + bb[it % 3][c][3];
                x0 = fmaxf(x0, 0.01f * x0);
                x1 = fmaxf(x1, 0.01f * x1);
                x2 = fmaxf(x2, 0.01f * x2);
                x3 = fmaxf(x3, 0.01f * x3);
                tc[c] = (x0 * wa_s[c][0] + x1 * wa_s[c][1])
                      + (x2 * wa_s[c][2] + x3 * wa_s[c][3]);
            }
            float part = (tc[0] + tc[1]) + (tc[2] + tc[3]);
            part += __shfl_xor(part, 16);
            part += __shfl_xor(part, 32);
            if (l < 16) lgP[ii][j0 + l] = part;
        }
        __builtin_amdgcn_s_setprio(0);
    }
    __syncthreads();

    // ---- Pass B: masked softmax, wave wv owns row (wv&1), half (wv>>1) ----
    {
        const int rw = wv & 1, h = wv >> 1;
        const int c0 = h * 512 + l * 4;
        const size_t arb = (size_t)(b * N_ + i0 + rw) * N_;
        float4 lv[2], av[2];
        #pragma unroll
        for (int q = 0; q < 2; ++q) {
            lv[q] = *(const float4*)&lgP[rw][c0 + 256 * q];
            av[q] = *(const float4*)&adj[arb + c0 + 256 * q];
        }
        const float NEG = -3.4e38f;
        float m = NEG;
        #pragma unroll
        for (int q = 0; q < 2; ++q) {
            m = fmaxf(m, av[q].x > 0.f ? lv[q].x : NEG);
            m = fmaxf(m, av[q].y > 0.f ? lv[q].y : NEG);
            m = fmaxf(m, av[q].z > 0.f ? lv[q].z : NEG);
            m = fmaxf(m, av[q].w > 0.f ? lv[q].w : NEG);
        }
        #pragma unroll
        for (int o = 1; o < 64; o <<= 1) m = fmaxf(m, __shfl_xor(m, o));
        if (l == 0) pmax[wv] = m;
        __syncthreads();
        m = fmaxf(pmax[rw], pmax[2 + rw]);
        float sum = 0.f;
        #pragma unroll
        for (int q = 0; q < 2; ++q) {
            float4 e4;
            e4.x = av[q].x > 0.f ? __expf(lv[q].x - m) : 0.f;
            e4.y = av[q].y > 0.f ? __expf(lv[q].y - m) : 0.f;
            e4.z = av[q].z > 0.f ? __expf(lv[q].z - m) : 0.f;
            e4.w = av[q].w > 0.f ? __expf(lv[q].w - m) : 0.f;
            *(float4*)&lgP[rw][c0 + 256 * q] = e4;
            sum += (e4.x + e4.y) + (e4.z + e4.w);
        }
        #pragma unroll
        for (int o = 1; o < 64; o <<= 1) sum += __shfl_xor(sum, o);
        if (l == 0) psum[wv] = sum;
        __syncthreads();
        if (t < TI_) sinv[t] = 1.0f / (psum[t] + psum[t + 2]);
        // lgP exp-writes are pre-psum-barrier; sinv read after redv barrier.
    }

    // ---- Pass C: (exp @ values), k order staggered per block ----
    const int cg = l & 15, jp = l >> 4, ch0 = cg * 8;
    const int phC = r & 63;
    float acc[TI_][8] = {};
    const float* vb = values + (size_t)b * N_ * OUT_ + ch0;
    for (int k = 0; k < 64; ++k) {
        const int kp = (k + phC) & 63;
        const int j = wv * 4 + jp + kp * 16;
        float cw[TI_];
        #pragma unroll
        for (int ii = 0; ii < TI_; ++ii) cw[ii] = lgP[ii][j];
        const float* vp = vb + (size_t)j * OUT_;
        const float4 v0 = *(const float4*)vp;
        const float4 v1 = *(const float4*)(vp + 4);
        const float vv[8] = {v0.x, v0.y, v0.z, v0.w, v1.x, v1.y, v1.z, v1.w};
        #pragma unroll
        for (int ii = 0; ii < TI_; ++ii)
            #pragma unroll
            for (int kk = 0; kk < 8; ++kk)
                acc[ii][kk] += cw[ii] * vv[kk];
    }
    #pragma unroll
    for (int ii = 0; ii < TI_; ++ii)
        #pragma unroll
        for (int kk = 0; kk < 8; ++kk) {
            acc[ii][kk] += __shfl_xor(acc[ii][kk], 16);
            acc[ii][kk] += __shfl_xor(acc[ii][kk], 32);
        }
    if (l < 16) {
        #pragma unroll
        for (int ii = 0; ii < TI_; ++ii)
            #pragma unroll
            for (int q = 0; q < 2; ++q) {
                float4 w4 = make_float4(acc[ii][q * 4], acc[ii][q * 4 + 1],
                                        acc[ii][q * 4 + 2], acc[ii][q * 4 + 3]);
                *(float4*)&redv[wv][l][ii * 8 + q * 4] = w4;
            }
    }
    __syncthreads();
    {
        const int ch = t & 127, g = ch >> 3, kk = ch & 7;
        const int ii = t >> 7;                        // 0..1
        float sum = redv[0][g][ii * 8 + kk];
        #pragma unroll
        for (int w = 1; w < 4; ++w) sum += redv[w][g][ii * 8 + kk];
        const size_t ob = ((size_t)(b * N_ + i0 + ii)) * OUT_ + ch;
        out[ob] = fmaxf(sum * sinv[ii] + skipo[ob], 0.f);
    }
}

extern "C" void kernel_launch(void* const* d_in, const int* in_sizes, int n_in,
                              void* d_out, int out_size, void* d_ws, size_t ws_size,
                              hipStream_t stream) {
    const float* features   = (const float*)d_in[0];
    const float* e_features = (const float*)d_in[1];
    const float* g_features = (const float*)d_in[2];
    const float* adj        = (const float*)d_in[3];
    const float* Wm    = (const float*)d_in[4];
    const float* bm    = (const float*)d_in[5];
    const float* Wskip = (const float*)d_in[6];
    const float* bskip = (const float*)d_in[7];
    const float* W1    = (const float*)d_in[8];
    const float* b1    = (const float*)d_in[9];
    const float* W2    = (const float*)d_in[10];
    const float* b2    = (const float*)d_in[11];
    const float* We    = (const float*)d_in[12];
    const float* be    = (const float*)d_in[13];
    const float* Wg    = (const float*)d_in[14];
    const float* bg    = (const float*)d_in[15];
    const float* Wa    = (const float*)d_in[16];
    float* out = (float*)d_out;

    float* ws      = (float*)d_ws;
    float* values  = ws;                    // 262144 floats
    float* skipo   = ws + 262144;           // 262144
    float* P1x     = ws + 524288;           // 131072 (row-major [node][mid])
    float* p2      = ws + 655360;           // 131072
    float* pg      = ws + 786432;           // 128
    short* We_frag = (short*)(ws + 786560); // 2048 shorts (1024 floats)

    prep_all<<<B_ * N_ / PR_ROWS + 2, 384, 0, stream>>>(
        features, g_features, Wm, bm, Wskip, bskip, W1, b1, W2, b2,
        We, be, Wg, bg, values, skipo, P1x, p2, pg, We_frag);
    gat_main<<<B_ * N_ / TI_, 256, 0, stream>>>(
        e_features, adj, We_frag, Wa, values, skipo, P1x, p2, pg, out);
}